// Round 9
// baseline (250.549 us; speedup 1.0000x reference)
//
#include <hip/hip_runtime.h>
#include <hip/hip_bf16.h>

#define S_LEN 2048
#define DMODEL 1024
#define NHEAD 16
#define DKEY 64

typedef __attribute__((ext_vector_type(8))) short bf16x8;
typedef __attribute__((ext_vector_type(4))) float f32x4;

__device__ __forceinline__ short f2bf(float f) {
  union { float f; unsigned u; } a; a.f = f;
  unsigned u = a.u;
  u += 0x7fff + ((u >> 16) & 1);   // RTNE
  return (short)(u >> 16);
}
__device__ __forceinline__ unsigned pk2bf(float a, float b) {
  union { __hip_bfloat162 h; unsigned u; } c;
  c.h = __float22bfloat162_rn(float2{a, b});
  return c.u;
}
__device__ __forceinline__ void gl_lds16(const void* g, void* l) {
  __builtin_amdgcn_global_load_lds(
      (const __attribute__((address_space(1))) unsigned int*)g,
      (__attribute__((address_space(3))) unsigned int*)l, 16, 0, 0);
}
#define EX2(x) __builtin_amdgcn_exp2f(x)

// ---------------------------------------------------------------------------
// Kernel 0 (fused): X fp32->bf16 (blocks 0..12287) + weight transpose/convert
// (blocks 12288..13311). Branch is block-uniform. One launch instead of two.
// ---------------------------------------------------------------------------
__global__ __launch_bounds__(256) void convert_xw(
    const float* __restrict__ q, const float* __restrict__ k,
    const float* __restrict__ v, const float* __restrict__ Wq,
    const float* __restrict__ Wk, const float* __restrict__ Wv,
    const float* __restrict__ Wo, short* __restrict__ Xb,
    short* __restrict__ Wt) {
  __shared__ short T[64][72];
  const int bid = blockIdx.x;
  const int t = threadIdx.x;
  if (bid < 12288) {
    const int z = bid >> 12;
    const int x = bid & 4095;
    const float* X = (z == 0) ? q : (z == 1) ? k : v;
    short* dst = Xb + (size_t)z * 4194304;
    const int i = (x * 256 + t) * 4;
    const float4 xv = *(const float4*)&X[i];
    uint2 o;
    o.x = pk2bf(xv.x, xv.y);
    o.y = pk2bf(xv.z, xv.w);
    *(uint2*)&dst[i] = o;
    return;
  }
  const int wid = bid - 12288;
  const int z = wid >> 8;
  const float* W = (z == 0) ? Wq : (z == 1) ? Wk : (z == 2) ? Wv : Wo;
  short* dst = Wt + (size_t)z * 1048576;
  const int k0 = ((wid >> 4) & 15) * 64, n0 = (wid & 15) * 64;
#pragma unroll
  for (int p = 0; p < 4; ++p) {
    const int r = p * 16 + (t >> 4), c = (t & 15) * 4;
    const float4 wv = *(const float4*)&W[(size_t)(k0 + r) * DMODEL + n0 + c];
    T[c + 0][r] = f2bf(wv.x);
    T[c + 1][r] = f2bf(wv.y);
    T[c + 2][r] = f2bf(wv.z);
    T[c + 3][r] = f2bf(wv.w);
  }
  __syncthreads();
  const int rr = t >> 2, cc = (t & 3) * 16;
  const bf16x8 x0 = *(const bf16x8*)&T[rr][cc];
  const bf16x8 x1 = *(const bf16x8*)&T[rr][cc + 8];
  short* d = dst + (size_t)(n0 + rr) * DMODEL + k0 + cc;
  *(bf16x8*)&d[0] = x0;
  *(bf16x8*)&d[8] = x1;
}

// ---------------------------------------------------------------------------
// Bf16 tile staging with bank-conflict-free XOR chunk swizzle (256 thr).
// Each thread issues exactly 2 global_load_lds.
// ---------------------------------------------------------------------------
__device__ __forceinline__ void stage_tile32(const short* gbase, short (*tile)[32],
                                             int w, int lane) {
  const int row = lane >> 2;                          // 0..15 per issue
  const int g = ((lane & 3) ^ ((row >> 1) & 3)) * 8;  // swizzled global chunk
#pragma unroll
  for (int i = 0; i < 2; ++i) {
    const int r = w * 32 + i * 16 + row;
    gl_lds16(gbase + (size_t)r * DMODEL + g, &tile[w * 32 + i * 16][0]);
  }
}

// 512-thread variant: 1 load per thread per tile, wave-linear LDS dest.
__device__ __forceinline__ void stage_tile32_512(const short* gbase,
                                                 short (*tile)[32], int t) {
  const int row = t >> 2;                             // 0..127
  const int g = ((t & 3) ^ ((row >> 1) & 3)) * 8;
  gl_lds16(gbase + (size_t)row * DMODEL + g, &tile[row][0]);
}

// ---------------------------------------------------------------------------
// Kernel 1: QKV projection (R3-proven form). 128x128 tile, BK=32, all-bf16,
// 3-deep ring + counted vmcnt. Q/K epilogue: f32 LDS transpose, vectorized
// rope, coalesced 16B stores. z=0 Q (RoPE+exp2 scale), z=1 K (RoPE), z=2 V^T.
// ---------------------------------------------------------------------------
__global__ __launch_bounds__(256) void gemm_qkv(
    const short* __restrict__ Xb, const short* __restrict__ Wt,
    const float* __restrict__ bq, const float* __restrict__ bk,
    const float* __restrict__ bv, const float* __restrict__ rope,
    short* __restrict__ Qw, short* __restrict__ Kw, short* __restrict__ Vw) {
  __shared__ char smem[49152];   // 3 ring buffers x (A 8KB + B 8KB)

  const int z = blockIdx.z;
  const short* X = Xb + (size_t)z * 4194304;
  const float* bias = (z == 0) ? bq : (z == 1) ? bk : bv;
  const short* Wz = Wt + (size_t)z * 1048576;

  const int m0 = blockIdx.x * 128, n0 = blockIdx.y * 128;
  const int t = threadIdx.x;
  const int lane = t & 63;
  const int w = t >> 6;
  const int quad = lane >> 4;
  const int l15 = lane & 15;
  const int wr = (w >> 1) * 64, wc = (w & 1) * 64;
  const int rswz = (quad ^ ((l15 >> 1) & 3)) * 8;  // frag-read swizzled offset

  const short* Abase = X + (size_t)m0 * DMODEL;
  const short* Bbase = Wz + (size_t)n0 * DMODEL;

  f32x4 acc[4][4] = {};

  // prologue: tiles 0 and 1 into ring slots 0,1
  stage_tile32(Abase + 0, (short(*)[32])(smem + 0), w, lane);
  stage_tile32(Bbase + 0, (short(*)[32])(smem + 8192), w, lane);
  stage_tile32(Abase + 32, (short(*)[32])(smem + 16384), w, lane);
  stage_tile32(Bbase + 32, (short(*)[32])(smem + 16384 + 8192), w, lane);

  unsigned oc = 0, on = 16384, of = 32768;   // cur / next / future offsets
  for (int it = 0; it < 32; ++it) {
    if (it < 30) {
      const int kt = (it + 2) * 32;
      stage_tile32(Abase + kt, (short(*)[32])(smem + of), w, lane);
      stage_tile32(Bbase + kt, (short(*)[32])(smem + of + 8192), w, lane);
    }
    if (it < 30)       asm volatile("s_waitcnt vmcnt(8)" ::: "memory");
    else if (it == 30) asm volatile("s_waitcnt vmcnt(4)" ::: "memory");
    else               asm volatile("s_waitcnt vmcnt(0)" ::: "memory");
    __builtin_amdgcn_s_barrier();
    short (*As)[32] = (short(*)[32])(smem + oc);
    short (*Bs)[32] = (short(*)[32])(smem + oc + 8192);
    bf16x8 bf[4], af[4];
#pragma unroll
    for (int nj = 0; nj < 4; ++nj)
      bf[nj] = *(const bf16x8*)&Bs[wc + nj * 16 + l15][rswz];
#pragma unroll
    for (int mi = 0; mi < 4; ++mi)
      af[mi] = *(const bf16x8*)&As[wr + mi * 16 + l15][rswz];
#pragma unroll
    for (int mi = 0; mi < 4; ++mi)
#pragma unroll
      for (int nj = 0; nj < 4; ++nj)
        acc[mi][nj] =
            __builtin_amdgcn_mfma_f32_16x16x32_bf16(af[mi], bf[nj], acc[mi][nj], 0, 0, 0);
    asm volatile("s_waitcnt lgkmcnt(0)" ::: "memory");
    __builtin_amdgcn_s_barrier();
    const unsigned tmp = oc; oc = on; on = of; of = tmp;
  }

  const int b = (m0 + wr) >> 11;
  const int sbase = (m0 + wr) & 2047;

  if (z == 2) {
    __syncthreads();
    short (*tr)[72] = (short(*)[72])(smem + w * 9216);
    const int h2 = (n0 + wc) >> 6;
#pragma unroll
    for (int nj = 0; nj < 4; ++nj) {
      const float bval = bias[n0 + wc + nj * 16 + l15];
#pragma unroll
      for (int ti = 0; ti < 4; ++ti)
#pragma unroll
        for (int r = 0; r < 4; ++r)
          tr[nj * 16 + l15][ti * 16 + quad * 4 + r] = f2bf(acc[ti][nj][r] + bval);
    }
    asm volatile("s_waitcnt lgkmcnt(0)" ::: "memory");
    const int bh2 = b * NHEAD + h2;
#pragma unroll
    for (int cc = 0; cc < 4; ++cc) {
      const int row = cc * 16 + (lane >> 2);
      const int c0 = (lane & 3) * 16;
      const bf16x8 x0 = *(const bf16x8*)&tr[row][c0];
      const bf16x8 x1 = *(const bf16x8*)&tr[row][c0 + 8];
      short* d = Vw + ((size_t)bh2 * DKEY + row) * S_LEN + sbase + c0;
      *(bf16x8*)&d[0] = x0;
      *(bf16x8*)&d[8] = x1;
    }
    return;
  }

  // ---- Q/K epilogue: f32 LDS transpose + vectorized rope + coalesced store
  short* outw = (z == 0) ? Qw : Kw;
  const float qs = (z == 0) ? 0.18033688011112042f : 1.0f;  // log2(e)/8 for Q
  const int h = (n0 + wc) >> 6;
  const int bh = b * NHEAD + h;
  float (*tqf)[33] = (float(*)[33])(smem + w * 8448);   // per-wave, 8448 B
#pragma unroll
  for (int half = 0; half < 2; ++half) {
    asm volatile("s_waitcnt lgkmcnt(0)" ::: "memory");   // WAR vs prev reads
#pragma unroll
    for (int nj2 = 0; nj2 < 2; ++nj2) {
      const int nj = half * 2 + nj2;
      const float bval = bias[n0 + wc + nj * 16 + l15];
#pragma unroll
      for (int ti = 0; ti < 4; ++ti)
#pragma unroll
        for (int r = 0; r < 4; ++r)
          tqf[ti * 16 + quad * 4 + r][nj2 * 16 + l15] =
              (acc[ti][nj][r] + bval) * qs;
    }
    asm volatile("s_waitcnt lgkmcnt(0)" ::: "memory");
    const int row = lane;                    // one s-row per lane
    float vv[32];
#pragma unroll
    for (int i = 0; i < 8; ++i) {
      const float4 x = *(const float4*)&tqf[row][i * 4];
      vv[i * 4 + 0] = x.x; vv[i * 4 + 1] = x.y;
      vv[i * 4 + 2] = x.z; vv[i * 4 + 3] = x.w;
    }
    const int s = sbase + row;
    const float* rp = &rope[((size_t)b * S_LEN + s) * DKEY + half * 32];
    short* d = outw + ((size_t)bh * S_LEN + s) * DKEY + half * 32;
#pragma unroll
    for (int i = 0; i < 4; ++i) {            // 8 dk per i
      const float4 ra = *(const float4*)&rp[i * 8];
      const float4 rb = *(const float4*)&rp[i * 8 + 4];
      uint4 o;
      o.x = pk2bf(vv[i*8+0]*ra.y - vv[i*8+1]*ra.x, vv[i*8+1]*ra.y + vv[i*8+0]*ra.x);
      o.y = pk2bf(vv[i*8+2]*ra.w - vv[i*8+3]*ra.z, vv[i*8+3]*ra.w + vv[i*8+2]*ra.z);
      o.z = pk2bf(vv[i*8+4]*rb.y - vv[i*8+5]*rb.x, vv[i*8+5]*rb.y + vv[i*8+4]*rb.x);
      o.w = pk2bf(vv[i*8+6]*rb.w - vv[i*8+7]*rb.z, vv[i*8+7]*rb.w + vv[i*8+6]*rb.z);
      *(uint4*)&d[i * 8] = o;
    }
  }
}

// ---------------------------------------------------------------------------
// Kernel 2: causal flash attention -- measured-best 4-wave 16x16 structure.
// ---------------------------------------------------------------------------
__global__ __launch_bounds__(256, 4) void attn_kernel(
    const short* __restrict__ Qw, const short* __restrict__ Kw,
    const short* __restrict__ Vw, const float* __restrict__ v_mask,
    short* __restrict__ Ow) {
  __shared__ short Kt[2][64][64];
  __shared__ short Vt[2][64][64];
  __shared__ short Sb[4][16][64];   // XOR chunk-swizzled: chunk ^= (row & 7)

  const int t = threadIdx.x;
  const int w = t >> 6;
  const int lane = t & 63;
  const int quad = lane >> 4;
  const int l15 = lane & 15;
  const int x8 = l15 & 7;
  const int bh = blockIdx.y;
  const int b = bh >> 4;
  const int h = bh & 15;

  // balanced chunk map: co-resident blocks get {x, x^31, x^16, x^31^16}
  int c = blockIdx.x;
  const int jj = blockIdx.y >> 3;
  if (jj & 1) c ^= 31;
  if (jj & 2) c ^= 16;

  const short* Kbase = Kw + (size_t)bh * S_LEN * DKEY;
  const short* Vbase = Vw + (size_t)bh * DKEY * S_LEN;
  const float* vmb = v_mask + (size_t)b * S_LEN;

  const int sRow = lane >> 3;
  const int sCh = (lane & 7) ^ sRow;

  const int qb = c * 64;
  const int qrow = qb + w * 16 + l15;

  const short* Qp = Qw + ((size_t)bh * S_LEN + qrow) * DKEY;
  const bf16x8 q_lo = *(const bf16x8*)(Qp + quad * 8);
  const bf16x8 q_hi = *(const bf16x8*)(Qp + 32 + quad * 8);

  // block-uniform v_mask shortcut: exact iff every element == 1.0f
  float s32 = 0.f;
  {
    const float4* vm4 = (const float4*)vmb;
#pragma unroll
    for (int i = 0; i < 8; ++i) {
      const float4 a = vm4[lane * 8 + i];
      s32 += a.x + a.y + a.z + a.w;
    }
  }
  const bool vmall = __all(s32 == 32.0f);

  float m_i = -1.0e30f, l_i = 0.f;
  f32x4 acc[4] = {};

  const int niter = c + 1;
#pragma unroll
  for (int i = 0; i < 2; ++i) {
    const int kr = w * 16 + i * 8 + sRow;
    gl_lds16(Kbase + (size_t)kr * DKEY + sCh * 8, &Kt[0][w * 16 + i * 8][0]);
    gl_lds16(Vbase + (size_t)kr * S_LEN + sCh * 8, &Vt[0][w * 16 + i * 8][0]);
  }
  int cur = 0;
  for (int it = 0; it < niter; ++it) {
    const int j0 = it * 64;
    __syncthreads();
    if (it + 1 < niter) {
      const int jn = j0 + 64;
#pragma unroll
      for (int i = 0; i < 2; ++i) {
        const int kr = w * 16 + i * 8 + sRow;
        gl_lds16(Kbase + (size_t)(jn + kr) * DKEY + sCh * 8,
                 &Kt[cur ^ 1][w * 16 + i * 8][0]);
        gl_lds16(Vbase + (size_t)kr * S_LEN + jn + sCh * 8,
                 &Vt[cur ^ 1][w * 16 + i * 8][0]);
      }
    }
    bf16x8 ka[4][2];
#pragma unroll
    for (int kt = 0; kt < 4; ++kt) {
      ka[kt][0] = *(const bf16x8*)&Kt[cur][kt * 16 + l15][(quad ^ x8) * 8];
      ka[kt][1] = *(const bf16x8*)&Kt[cur][kt * 16 + l15][((4 + quad) ^ x8) * 8];
    }
    f32x4 sv[4];
    __builtin_amdgcn_s_setprio(1);
#pragma unroll
    for (int kt = 0; kt < 4; ++kt) {
      f32x4 s = {};
      s = __builtin_amdgcn_mfma_f32_16x16x32_bf16(ka[kt][0], q_lo, s, 0, 0, 0);
      s = __builtin_amdgcn_mfma_f32_16x16x32_bf16(ka[kt][1], q_hi, s, 0, 0, 0);
      sv[kt] = s;
    }
    __builtin_amdgcn_s_setprio(0);
    if (!vmall) {
#pragma unroll
      for (int kt = 0; kt < 4; ++kt) {
        const float4 vm = *(const float4*)&vmb[j0 + kt * 16 + quad * 4];
#pragma unroll
        for (int r = 0; r < 4; ++r)
          sv[kt][r] += (vm[r] - 1.0f) * 1.0e12f;
      }
    }
    if (it == c) {  // diagonal tile: only place causal mask can trigger
#pragma unroll
      for (int kt = 0; kt < 4; ++kt)
#pragma unroll
        for (int r = 0; r < 4; ++r) {
          const int kc = j0 + kt * 16 + quad * 4 + r;
          if (kc > qrow) sv[kt][r] = -1.0e12f;
        }
    }
    float mk[4];
#pragma unroll
    for (int kt = 0; kt < 4; ++kt)
      mk[kt] = fmaxf(fmaxf(sv[kt][0], sv[kt][1]), fmaxf(sv[kt][2], sv[kt][3]));
    const float mloc = fmaxf(fmaxf(mk[0], mk[1]), fmaxf(mk[2], mk[3]));
    float mt = fmaxf(mloc, __shfl_xor(mloc, 16));
    mt = fmaxf(mt, __shfl_xor(mt, 32));
    if (!__all(mt <= m_i + 8.0f)) {     // defer-max rescale
      const float mn = fmaxf(m_i, mt);
      const float alpha = EX2(m_i - mn);
      l_i *= alpha;
#pragma unroll
      for (int dt = 0; dt < 4; ++dt)
#pragma unroll
        for (int r = 0; r < 4; ++r) acc[dt][r] *= alpha;
      m_i = mn;
    }
    float sl = 0.f;
#pragma unroll
    for (int kt = 0; kt < 4; ++kt)
#pragma unroll
      for (int r = 0; r < 4; ++r) {
        sv[kt][r] = EX2(sv[kt][r] - m_i);
        sl += sv[kt][r];
      }
    sl += __shfl_xor(sl, 16);
    sl += __shfl_xor(sl, 32);
    l_i += sl;
#pragma unroll
    for (int kt = 0; kt < 4; ++kt) {
      uint2 pw;
      pw.x = pk2bf(sv[kt][0], sv[kt][1]);
      pw.y = pk2bf(sv[kt][2], sv[kt][3]);
      *(uint2*)&Sb[w][l15][(((2 * kt + (quad >> 1)) ^ x8) * 8) + (quad & 1) * 4] = pw;
    }
    asm volatile("s_waitcnt lgkmcnt(0)" ::: "memory");
    const bf16x8 pf0 = *(const bf16x8*)&Sb[w][l15][(quad ^ x8) * 8];
    const bf16x8 pf1 = *(const bf16x8*)&Sb[w][l15][((4 + quad) ^ x8) * 8];
    __builtin_amdgcn_s_setprio(1);
#pragma unroll
    for (int dt = 0; dt < 4; ++dt) {
      const bf16x8 va0 =
          *(const bf16x8*)&Vt[cur][dt * 16 + l15][(quad ^ x8) * 8];
      acc[dt] = __builtin_amdgcn_mfma_f32_16x16x32_bf16(va0, pf0, acc[dt], 0, 0, 0);
      const bf16x8 va1 =
          *(const bf16x8*)&Vt[cur][dt * 16 + l15][((4 + quad) ^ x8) * 8];
      acc[dt] = __builtin_amdgcn_mfma_f32_16x16x32_bf16(va1, pf1, acc[dt], 0, 0, 0);
    }
    __builtin_amdgcn_s_setprio(0);
    cur ^= 1;
  }
  const float inv = 1.0f / l_i;
#pragma unroll
  for (int dt = 0; dt < 4; ++dt) {
    uint2 ov;
    ov.x = pk2bf(acc[dt][0] * inv, acc[dt][1] * inv);
    ov.y = pk2bf(acc[dt][2] * inv, acc[dt][3] * inv);
    *(uint2*)&Sb[w][l15][(((2 * dt + (quad >> 1)) ^ x8) * 8) + (quad & 1) * 4] = ov;
  }
  asm volatile("s_waitcnt lgkmcnt(0)" ::: "memory");
  const int qr2 = lane >> 2;
  const int cc2 = lane & 3;
  const bf16x8 o0 = *(const bf16x8*)&Sb[w][qr2][((2 * cc2) ^ (qr2 & 7)) * 8];
  const bf16x8 o1 = *(const bf16x8*)&Sb[w][qr2][((2 * cc2 + 1) ^ (qr2 & 7)) * 8];
  short* dst =
      Ow + ((size_t)(b * S_LEN + qb + w * 16 + qr2)) * DMODEL + h * DKEY + cc2 * 16;
  *(bf16x8*)&dst[0] = o0;
  *(bf16x8*)&dst[8] = o1;
}

// ---------------------------------------------------------------------------
// Kernel 3: output projection -- 512 thr / 8 waves on 128x128 tile (2x
// waves/CU vs 4-wave version), 4-deep ring, 1 load/thread/tile staging.
// ---------------------------------------------------------------------------
__global__ __launch_bounds__(512) void gemm_out(
    const short* __restrict__ A, const short* __restrict__ Wz,
    const float* __restrict__ bias, float* __restrict__ out) {
  __shared__ char smem[65536];   // 4 ring buffers x (A 8KB + B 8KB)

  const int m0 = blockIdx.x * 128, n0 = blockIdx.y * 128;
  const int t = threadIdx.x;
  const int lane = t & 63;
  const int w = t >> 6;          // 0..7
  const int quad = lane >> 4;
  const int l15 = lane & 15;
  const int wr = (w >> 2) * 64, wc = (w & 3) * 32;
  const int rswz = (quad ^ ((l15 >> 1) & 3)) * 8;

  const short* Abase = A + (size_t)m0 * DMODEL;
  const short* Bbase = Wz + (size_t)n0 * DMODEL;

  f32x4 acc[4][2] = {};

#pragma unroll
  for (int p = 0; p < 3; ++p) {
    stage_tile32_512(Abase + p * 32, (short(*)[32])(smem + p * 16384), t);
    stage_tile32_512(Bbase + p * 32, (short(*)[32])(smem + p * 16384 + 8192), t);
  }

  unsigned o0 = 0, o1 = 16384, o2 = 32768, o3 = 49152;
  for (int it = 0; it < 32; ++it) {
    if (it < 29) {
      const int kt = (it + 3) * 32;
      stage_tile32_512(Abase + kt, (short(*)[32])(smem + o3), t);
      stage_tile32_512(Bbase + kt, (short(*)[32])(smem + o3 + 8192), t);
    }
    if (it < 29)       asm volatile("s_waitcnt vmcnt(6)" ::: "memory");
    else if (it == 29) asm volatile("s_waitcnt vmcnt(4)" ::: "memory");
    else if (it == 30) asm volatile("s_waitcnt vmcnt(2)" ::: "memory");
    else               asm volatile("s_waitcnt vmcnt(0)" ::: "memory");
    __builtin_amdgcn_s_barrier();
    short (*As)[32] = (short(*)[32])(smem + o0);
    short (*Bs)[32] = (short(*)[32])(smem + o0 + 8192);
    bf16x8 bf[2], af[4];
#pragma unroll
    for (int nj = 0; nj < 2; ++nj)
      bf[nj] = *(const bf16x8*)&Bs[wc + nj * 16 + l15][rswz];
#pragma unroll
    for (int mi = 0; mi < 4; ++mi)
      af[mi] = *(const bf16x8*)&As[wr + mi * 16 + l15][rswz];
#pragma unroll
    for (int mi = 0; mi < 4; ++mi)
#pragma unroll
      for (int nj = 0; nj < 2; ++nj)
        acc[mi][nj] =
            __builtin_amdgcn_mfma_f32_16x16x32_bf16(af[mi], bf[nj], acc[mi][nj], 0, 0, 0);
    asm volatile("s_waitcnt lgkmcnt(0)" ::: "memory");
    __builtin_amdgcn_s_barrier();
    const unsigned tmp = o0; o0 = o1; o1 = o2; o2 = o3; o3 = tmp;
  }
#pragma unroll
  for (int nj = 0; nj < 2; ++nj) {
    const int n = n0 + wc + nj * 16 + l15;
    const float bval = bias[n];
#pragma unroll
    for (int ti = 0; ti < 4; ++ti)
#pragma unroll
      for (int r = 0; r < 4; ++r) {
        const int m = m0 + wr + ti * 16 + quad * 4 + r;
        out[(size_t)m * DMODEL + n] = acc[ti][nj][r] + bval;
      }
  }
}

// ---------------------------------------------------------------------------
extern "C" void kernel_launch(void* const* d_in, const int* in_sizes, int n_in,
                              void* d_out, int out_size, void* d_ws,
                              size_t ws_size, hipStream_t stream) {
  const float* q      = (const float*)d_in[0];
  const float* k      = (const float*)d_in[1];
  const float* v      = (const float*)d_in[2];
  const float* rope   = (const float*)d_in[3];
  const float* v_mask = (const float*)d_in[5];
  const float* Wq = (const float*)d_in[6];
  const float* bq = (const float*)d_in[7];
  const float* Wk = (const float*)d_in[8];
  const float* bk = (const float*)d_in[9];
  const float* Wv = (const float*)d_in[10];
  const float* bv = (const float*)d_in[11];
  const float* Wo = (const float*)d_in[12];
  const float* bo = (const float*)d_in[13];
  float* out = (float*)d_out;

  short* ws = (short*)d_ws;
  short* Qw = ws;                  // [bh][s][dk] bf16, 8 MB
  short* Kw = ws + 4194304;        // [bh][s][dk] bf16, 8 MB
  short* Vw = ws + 8388608;        // [bh][dk][s] bf16, 8 MB
  short* Ow = ws + 12582912;       // [b][s][dmodel] bf16, 8 MB
  short* Wt = ws + 16777216;       // 4x [n][k] bf16, 8 MB
  short* Xb = ws + 20971520;       // 3x [m][k] bf16, 24 MB  (total 64 MB)

  convert_xw<<<dim3(13312), 256, 0, stream>>>(q, k, v, Wq, Wk, Wv, Wo, Xb, Wt);
  gemm_qkv<<<dim3(32, 8, 3), 256, 0, stream>>>(Xb, Wt, bq, bk, bv, rope,
                                               Qw, Kw, Vw);
  attn_kernel<<<dim3(32, 32), 256, 0, stream>>>(Qw, Kw, Vw, v_mask, Ow);
  gemm_out<<<dim3(32, 8), 512, 0, stream>>>(Ow, Wt + 3145728, bo, out);
}

// Round 10
// 245.975 us; speedup vs baseline: 1.0186x; 1.0186x over previous
//
#include <hip/hip_runtime.h>
#include <hip/hip_bf16.h>

#define S_LEN 2048
#define DMODEL 1024
#define NHEAD 16
#define DKEY 64

typedef __attribute__((ext_vector_type(8))) short bf16x8;
typedef __attribute__((ext_vector_type(4))) float f32x4;

__device__ __forceinline__ short f2bf(float f) {
  union { float f; unsigned u; } a; a.f = f;
  unsigned u = a.u;
  u += 0x7fff + ((u >> 16) & 1);   // RTNE
  return (short)(u >> 16);
}
__device__ __forceinline__ unsigned pk2bf(float a, float b) {
  union { __hip_bfloat162 h; unsigned u; } c;
  c.h = __float22bfloat162_rn(float2{a, b});
  return c.u;
}
__device__ __forceinline__ void gl_lds16(const void* g, void* l) {
  __builtin_amdgcn_global_load_lds(
      (const __attribute__((address_space(1))) unsigned int*)g,
      (__attribute__((address_space(3))) unsigned int*)l, 16, 0, 0);
}
#define EX2(x) __builtin_amdgcn_exp2f(x)

// ---------------------------------------------------------------------------
// Kernel 0 (fused): X fp32->bf16 (blocks 0..12287) + weight transpose/convert
// (blocks 12288..13311). Branch is block-uniform. One launch instead of two.
// ---------------------------------------------------------------------------
__global__ __launch_bounds__(256) void convert_xw(
    const float* __restrict__ q, const float* __restrict__ k,
    const float* __restrict__ v, const float* __restrict__ Wq,
    const float* __restrict__ Wk, const float* __restrict__ Wv,
    const float* __restrict__ Wo, short* __restrict__ Xb,
    short* __restrict__ Wt) {
  __shared__ short T[64][72];
  const int bid = blockIdx.x;
  const int t = threadIdx.x;
  if (bid < 12288) {
    const int z = bid >> 12;
    const int x = bid & 4095;
    const float* X = (z == 0) ? q : (z == 1) ? k : v;
    short* dst = Xb + (size_t)z * 4194304;
    const int i = (x * 256 + t) * 4;
    const float4 xv = *(const float4*)&X[i];
    uint2 o;
    o.x = pk2bf(xv.x, xv.y);
    o.y = pk2bf(xv.z, xv.w);
    *(uint2*)&dst[i] = o;
    return;
  }
  const int wid = bid - 12288;
  const int z = wid >> 8;
  const float* W = (z == 0) ? Wq : (z == 1) ? Wk : (z == 2) ? Wv : Wo;
  short* dst = Wt + (size_t)z * 1048576;
  const int k0 = ((wid >> 4) & 15) * 64, n0 = (wid & 15) * 64;
#pragma unroll
  for (int p = 0; p < 4; ++p) {
    const int r = p * 16 + (t >> 4), c = (t & 15) * 4;
    const float4 wv = *(const float4*)&W[(size_t)(k0 + r) * DMODEL + n0 + c];
    T[c + 0][r] = f2bf(wv.x);
    T[c + 1][r] = f2bf(wv.y);
    T[c + 2][r] = f2bf(wv.z);
    T[c + 3][r] = f2bf(wv.w);
  }
  __syncthreads();
  const int rr = t >> 2, cc = (t & 3) * 16;
  const bf16x8 x0 = *(const bf16x8*)&T[rr][cc];
  const bf16x8 x1 = *(const bf16x8*)&T[rr][cc + 8];
  short* d = dst + (size_t)(n0 + rr) * DMODEL + k0 + cc;
  *(bf16x8*)&d[0] = x0;
  *(bf16x8*)&d[8] = x1;
}

// ---------------------------------------------------------------------------
// Bf16 tile staging with bank-conflict-free XOR chunk swizzle (256 thr).
// Each thread issues exactly 2 global_load_lds.
// ---------------------------------------------------------------------------
__device__ __forceinline__ void stage_tile32(const short* gbase, short (*tile)[32],
                                             int w, int lane) {
  const int row = lane >> 2;                          // 0..15 per issue
  const int g = ((lane & 3) ^ ((row >> 1) & 3)) * 8;  // swizzled global chunk
#pragma unroll
  for (int i = 0; i < 2; ++i) {
    const int r = w * 32 + i * 16 + row;
    gl_lds16(gbase + (size_t)r * DMODEL + g, &tile[w * 32 + i * 16][0]);
  }
}

// 512-thread variant: 1 load per thread per tile, wave-linear LDS dest.
__device__ __forceinline__ void stage_tile32_512(const short* gbase,
                                                 short (*tile)[32], int t) {
  const int row = t >> 2;                             // 0..127
  const int g = ((t & 3) ^ ((row >> 1) & 3)) * 8;
  gl_lds16(gbase + (size_t)row * DMODEL + g, &tile[row][0]);
}

// ---------------------------------------------------------------------------
// Kernel 1: QKV projection (R3-proven form). 128x128 tile, BK=32, all-bf16,
// 3-deep ring + counted vmcnt. Q/K epilogue: f32 LDS transpose, vectorized
// rope, coalesced 16B stores. z=0 Q (RoPE+exp2 scale), z=1 K (RoPE), z=2 V^T.
// ---------------------------------------------------------------------------
__global__ __launch_bounds__(256) void gemm_qkv(
    const short* __restrict__ Xb, const short* __restrict__ Wt,
    const float* __restrict__ bq, const float* __restrict__ bk,
    const float* __restrict__ bv, const float* __restrict__ rope,
    short* __restrict__ Qw, short* __restrict__ Kw, short* __restrict__ Vw) {
  __shared__ char smem[49152];   // 3 ring buffers x (A 8KB + B 8KB)

  const int z = blockIdx.z;
  const short* X = Xb + (size_t)z * 4194304;
  const float* bias = (z == 0) ? bq : (z == 1) ? bk : bv;
  const short* Wz = Wt + (size_t)z * 1048576;

  const int m0 = blockIdx.x * 128, n0 = blockIdx.y * 128;
  const int t = threadIdx.x;
  const int lane = t & 63;
  const int w = t >> 6;
  const int quad = lane >> 4;
  const int l15 = lane & 15;
  const int wr = (w >> 1) * 64, wc = (w & 1) * 64;
  const int rswz = (quad ^ ((l15 >> 1) & 3)) * 8;  // frag-read swizzled offset

  const short* Abase = X + (size_t)m0 * DMODEL;
  const short* Bbase = Wz + (size_t)n0 * DMODEL;

  f32x4 acc[4][4] = {};

  // prologue: tiles 0 and 1 into ring slots 0,1
  stage_tile32(Abase + 0, (short(*)[32])(smem + 0), w, lane);
  stage_tile32(Bbase + 0, (short(*)[32])(smem + 8192), w, lane);
  stage_tile32(Abase + 32, (short(*)[32])(smem + 16384), w, lane);
  stage_tile32(Bbase + 32, (short(*)[32])(smem + 16384 + 8192), w, lane);

  unsigned oc = 0, on = 16384, of = 32768;   // cur / next / future offsets
  for (int it = 0; it < 32; ++it) {
    if (it < 30) {
      const int kt = (it + 2) * 32;
      stage_tile32(Abase + kt, (short(*)[32])(smem + of), w, lane);
      stage_tile32(Bbase + kt, (short(*)[32])(smem + of + 8192), w, lane);
    }
    if (it < 30)       asm volatile("s_waitcnt vmcnt(8)" ::: "memory");
    else if (it == 30) asm volatile("s_waitcnt vmcnt(4)" ::: "memory");
    else               asm volatile("s_waitcnt vmcnt(0)" ::: "memory");
    __builtin_amdgcn_s_barrier();
    short (*As)[32] = (short(*)[32])(smem + oc);
    short (*Bs)[32] = (short(*)[32])(smem + oc + 8192);
    bf16x8 bf[4], af[4];
#pragma unroll
    for (int nj = 0; nj < 4; ++nj)
      bf[nj] = *(const bf16x8*)&Bs[wc + nj * 16 + l15][rswz];
#pragma unroll
    for (int mi = 0; mi < 4; ++mi)
      af[mi] = *(const bf16x8*)&As[wr + mi * 16 + l15][rswz];
#pragma unroll
    for (int mi = 0; mi < 4; ++mi)
#pragma unroll
      for (int nj = 0; nj < 4; ++nj)
        acc[mi][nj] =
            __builtin_amdgcn_mfma_f32_16x16x32_bf16(af[mi], bf[nj], acc[mi][nj], 0, 0, 0);
    asm volatile("s_waitcnt lgkmcnt(0)" ::: "memory");
    __builtin_amdgcn_s_barrier();
    const unsigned tmp = oc; oc = on; on = of; of = tmp;
  }

  const int b = (m0 + wr) >> 11;
  const int sbase = (m0 + wr) & 2047;

  if (z == 2) {
    __syncthreads();
    short (*tr)[72] = (short(*)[72])(smem + w * 9216);
    const int h2 = (n0 + wc) >> 6;
#pragma unroll
    for (int nj = 0; nj < 4; ++nj) {
      const float bval = bias[n0 + wc + nj * 16 + l15];
#pragma unroll
      for (int ti = 0; ti < 4; ++ti)
#pragma unroll
        for (int r = 0; r < 4; ++r)
          tr[nj * 16 + l15][ti * 16 + quad * 4 + r] = f2bf(acc[ti][nj][r] + bval);
    }
    asm volatile("s_waitcnt lgkmcnt(0)" ::: "memory");
    const int bh2 = b * NHEAD + h2;
#pragma unroll
    for (int cc = 0; cc < 4; ++cc) {
      const int row = cc * 16 + (lane >> 2);
      const int c0 = (lane & 3) * 16;
      const bf16x8 x0 = *(const bf16x8*)&tr[row][c0];
      const bf16x8 x1 = *(const bf16x8*)&tr[row][c0 + 8];
      short* d = Vw + ((size_t)bh2 * DKEY + row) * S_LEN + sbase + c0;
      *(bf16x8*)&d[0] = x0;
      *(bf16x8*)&d[8] = x1;
    }
    return;
  }

  // ---- Q/K epilogue: f32 LDS transpose + vectorized rope + coalesced store
  short* outw = (z == 0) ? Qw : Kw;
  const float qs = (z == 0) ? 0.18033688011112042f : 1.0f;  // log2(e)/8 for Q
  const int h = (n0 + wc) >> 6;
  const int bh = b * NHEAD + h;
  float (*tqf)[33] = (float(*)[33])(smem + w * 8448);   // per-wave, 8448 B
#pragma unroll
  for (int half = 0; half < 2; ++half) {
    asm volatile("s_waitcnt lgkmcnt(0)" ::: "memory");   // WAR vs prev reads
#pragma unroll
    for (int nj2 = 0; nj2 < 2; ++nj2) {
      const int nj = half * 2 + nj2;
      const float bval = bias[n0 + wc + nj * 16 + l15];
#pragma unroll
      for (int ti = 0; ti < 4; ++ti)
#pragma unroll
        for (int r = 0; r < 4; ++r)
          tqf[ti * 16 + quad * 4 + r][nj2 * 16 + l15] =
              (acc[ti][nj][r] + bval) * qs;
    }
    asm volatile("s_waitcnt lgkmcnt(0)" ::: "memory");
    const int row = lane;                    // one s-row per lane
    float vv[32];
#pragma unroll
    for (int i = 0; i < 8; ++i) {
      const float4 x = *(const float4*)&tqf[row][i * 4];
      vv[i * 4 + 0] = x.x; vv[i * 4 + 1] = x.y;
      vv[i * 4 + 2] = x.z; vv[i * 4 + 3] = x.w;
    }
    const int s = sbase + row;
    const float* rp = &rope[((size_t)b * S_LEN + s) * DKEY + half * 32];
    short* d = outw + ((size_t)bh * S_LEN + s) * DKEY + half * 32;
#pragma unroll
    for (int i = 0; i < 4; ++i) {            // 8 dk per i
      const float4 ra = *(const float4*)&rp[i * 8];
      const float4 rb = *(const float4*)&rp[i * 8 + 4];
      uint4 o;
      o.x = pk2bf(vv[i*8+0]*ra.y - vv[i*8+1]*ra.x, vv[i*8+1]*ra.y + vv[i*8+0]*ra.x);
      o.y = pk2bf(vv[i*8+2]*ra.w - vv[i*8+3]*ra.z, vv[i*8+3]*ra.w + vv[i*8+2]*ra.z);
      o.z = pk2bf(vv[i*8+4]*rb.y - vv[i*8+5]*rb.x, vv[i*8+5]*rb.y + vv[i*8+4]*rb.x);
      o.w = pk2bf(vv[i*8+6]*rb.w - vv[i*8+7]*rb.z, vv[i*8+7]*rb.w + vv[i*8+6]*rb.z);
      *(uint4*)&d[i * 8] = o;
    }
  }
}

// ---------------------------------------------------------------------------
// Kernel 2: causal flash attention -- measured-best 4-wave 16x16 structure,
// with two issue-order fixes: (a) V fragments read BEFORE softmax (the Sb
// lgkmcnt(0) asm fence otherwise pins them after the drain, exposing their
// ~120cyc LDS latency on the critical path every tile); (b) prefetch issue
// moved after the ka/va read issue so the first ds_read starts immediately.
// ---------------------------------------------------------------------------
__global__ __launch_bounds__(256, 4) void attn_kernel(
    const short* __restrict__ Qw, const short* __restrict__ Kw,
    const short* __restrict__ Vw, const float* __restrict__ v_mask,
    short* __restrict__ Ow) {
  __shared__ short Kt[2][64][64];
  __shared__ short Vt[2][64][64];
  __shared__ short Sb[4][16][64];   // XOR chunk-swizzled: chunk ^= (row & 7)

  const int t = threadIdx.x;
  const int w = t >> 6;
  const int lane = t & 63;
  const int quad = lane >> 4;
  const int l15 = lane & 15;
  const int x8 = l15 & 7;
  const int bh = blockIdx.y;
  const int b = bh >> 4;
  const int h = bh & 15;

  // balanced chunk map: co-resident blocks get {x, x^31, x^16, x^31^16}
  int c = blockIdx.x;
  const int jj = blockIdx.y >> 3;
  if (jj & 1) c ^= 31;
  if (jj & 2) c ^= 16;

  const short* Kbase = Kw + (size_t)bh * S_LEN * DKEY;
  const short* Vbase = Vw + (size_t)bh * DKEY * S_LEN;
  const float* vmb = v_mask + (size_t)b * S_LEN;

  const int sRow = lane >> 3;
  const int sCh = (lane & 7) ^ sRow;

  const int qb = c * 64;
  const int qrow = qb + w * 16 + l15;

  const short* Qp = Qw + ((size_t)bh * S_LEN + qrow) * DKEY;
  const bf16x8 q_lo = *(const bf16x8*)(Qp + quad * 8);
  const bf16x8 q_hi = *(const bf16x8*)(Qp + 32 + quad * 8);

  // block-uniform v_mask shortcut: exact iff every element == 1.0f
  float s32 = 0.f;
  {
    const float4* vm4 = (const float4*)vmb;
#pragma unroll
    for (int i = 0; i < 8; ++i) {
      const float4 a = vm4[lane * 8 + i];
      s32 += a.x + a.y + a.z + a.w;
    }
  }
  const bool vmall = __all(s32 == 32.0f);

  float m_i = -1.0e30f, l_i = 0.f;
  f32x4 acc[4] = {};

  const int niter = c + 1;
#pragma unroll
  for (int i = 0; i < 2; ++i) {
    const int kr = w * 16 + i * 8 + sRow;
    gl_lds16(Kbase + (size_t)kr * DKEY + sCh * 8, &Kt[0][w * 16 + i * 8][0]);
    gl_lds16(Vbase + (size_t)kr * S_LEN + sCh * 8, &Vt[0][w * 16 + i * 8][0]);
  }
  int cur = 0;
  for (int it = 0; it < niter; ++it) {
    const int j0 = it * 64;
    __syncthreads();
    // (a) issue current-tile LDS reads FIRST: K then V fragments.
    bf16x8 ka[4][2];
#pragma unroll
    for (int kt = 0; kt < 4; ++kt) {
      ka[kt][0] = *(const bf16x8*)&Kt[cur][kt * 16 + l15][(quad ^ x8) * 8];
      ka[kt][1] = *(const bf16x8*)&Kt[cur][kt * 16 + l15][((4 + quad) ^ x8) * 8];
    }
    bf16x8 vf[4][2];
#pragma unroll
    for (int dt = 0; dt < 4; ++dt) {
      vf[dt][0] = *(const bf16x8*)&Vt[cur][dt * 16 + l15][(quad ^ x8) * 8];
      vf[dt][1] = *(const bf16x8*)&Vt[cur][dt * 16 + l15][((4 + quad) ^ x8) * 8];
    }
    // (b) prefetch next tile AFTER the read issue; it has softmax+PV to land.
    if (it + 1 < niter) {
      const int jn = j0 + 64;
#pragma unroll
      for (int i = 0; i < 2; ++i) {
        const int kr = w * 16 + i * 8 + sRow;
        gl_lds16(Kbase + (size_t)(jn + kr) * DKEY + sCh * 8,
                 &Kt[cur ^ 1][w * 16 + i * 8][0]);
        gl_lds16(Vbase + (size_t)kr * S_LEN + jn + sCh * 8,
                 &Vt[cur ^ 1][w * 16 + i * 8][0]);
      }
    }
    f32x4 sv[4];
    __builtin_amdgcn_s_setprio(1);
#pragma unroll
    for (int kt = 0; kt < 4; ++kt) {
      f32x4 s = {};
      s = __builtin_amdgcn_mfma_f32_16x16x32_bf16(ka[kt][0], q_lo, s, 0, 0, 0);
      s = __builtin_amdgcn_mfma_f32_16x16x32_bf16(ka[kt][1], q_hi, s, 0, 0, 0);
      sv[kt] = s;
    }
    __builtin_amdgcn_s_setprio(0);
    if (!vmall) {
#pragma unroll
      for (int kt = 0; kt < 4; ++kt) {
        const float4 vm = *(const float4*)&vmb[j0 + kt * 16 + quad * 4];
#pragma unroll
        for (int r = 0; r < 4; ++r)
          sv[kt][r] += (vm[r] - 1.0f) * 1.0e12f;
      }
    }
    if (it == c) {  // diagonal tile: only place causal mask can trigger
#pragma unroll
      for (int kt = 0; kt < 4; ++kt)
#pragma unroll
        for (int r = 0; r < 4; ++r) {
          const int kc = j0 + kt * 16 + quad * 4 + r;
          if (kc > qrow) sv[kt][r] = -1.0e12f;
        }
    }
    float mk[4];
#pragma unroll
    for (int kt = 0; kt < 4; ++kt)
      mk[kt] = fmaxf(fmaxf(sv[kt][0], sv[kt][1]), fmaxf(sv[kt][2], sv[kt][3]));
    const float mloc = fmaxf(fmaxf(mk[0], mk[1]), fmaxf(mk[2], mk[3]));
    float mt = fmaxf(mloc, __shfl_xor(mloc, 16));
    mt = fmaxf(mt, __shfl_xor(mt, 32));
    if (!__all(mt <= m_i + 8.0f)) {     // defer-max rescale
      const float mn = fmaxf(m_i, mt);
      const float alpha = EX2(m_i - mn);
      l_i *= alpha;
#pragma unroll
      for (int dt = 0; dt < 4; ++dt)
#pragma unroll
        for (int r = 0; r < 4; ++r) acc[dt][r] *= alpha;
      m_i = mn;
    }
    float sl = 0.f;
#pragma unroll
    for (int kt = 0; kt < 4; ++kt)
#pragma unroll
      for (int r = 0; r < 4; ++r) {
        sv[kt][r] = EX2(sv[kt][r] - m_i);
        sl += sv[kt][r];
      }
    sl += __shfl_xor(sl, 16);
    sl += __shfl_xor(sl, 32);
    l_i += sl;
#pragma unroll
    for (int kt = 0; kt < 4; ++kt) {
      uint2 pw;
      pw.x = pk2bf(sv[kt][0], sv[kt][1]);
      pw.y = pk2bf(sv[kt][2], sv[kt][3]);
      *(uint2*)&Sb[w][l15][(((2 * kt + (quad >> 1)) ^ x8) * 8) + (quad & 1) * 4] = pw;
    }
    asm volatile("s_waitcnt lgkmcnt(0)" ::: "memory");
    const bf16x8 pf0 = *(const bf16x8*)&Sb[w][l15][(quad ^ x8) * 8];
    const bf16x8 pf1 = *(const bf16x8*)&Sb[w][l15][((4 + quad) ^ x8) * 8];
    __builtin_amdgcn_s_setprio(1);
#pragma unroll
    for (int dt = 0; dt < 4; ++dt) {
      acc[dt] = __builtin_amdgcn_mfma_f32_16x16x32_bf16(vf[dt][0], pf0, acc[dt], 0, 0, 0);
      acc[dt] = __builtin_amdgcn_mfma_f32_16x16x32_bf16(vf[dt][1], pf1, acc[dt], 0, 0, 0);
    }
    __builtin_amdgcn_s_setprio(0);
    cur ^= 1;
  }
  const float inv = 1.0f / l_i;
#pragma unroll
  for (int dt = 0; dt < 4; ++dt) {
    uint2 ov;
    ov.x = pk2bf(acc[dt][0] * inv, acc[dt][1] * inv);
    ov.y = pk2bf(acc[dt][2] * inv, acc[dt][3] * inv);
    *(uint2*)&Sb[w][l15][(((2 * dt + (quad >> 1)) ^ x8) * 8) + (quad & 1) * 4] = ov;
  }
  asm volatile("s_waitcnt lgkmcnt(0)" ::: "memory");
  const int qr2 = lane >> 2;
  const int cc2 = lane & 3;
  const bf16x8 o0 = *(const bf16x8*)&Sb[w][qr2][((2 * cc2) ^ (qr2 & 7)) * 8];
  const bf16x8 o1 = *(const bf16x8*)&Sb[w][qr2][((2 * cc2 + 1) ^ (qr2 & 7)) * 8];
  short* dst =
      Ow + ((size_t)(b * S_LEN + qb + w * 16 + qr2)) * DMODEL + h * DKEY + cc2 * 16;
  *(bf16x8*)&dst[0] = o0;
  *(bf16x8*)&dst[8] = o1;
}

// ---------------------------------------------------------------------------
// Kernel 3: output projection -- 512 thr / 8 waves on 128x128 tile,
// 4-deep ring, 1 load/thread/tile staging.
// ---------------------------------------------------------------------------
__global__ __launch_bounds__(512) void gemm_out(
    const short* __restrict__ A, const short* __restrict__ Wz,
    const float* __restrict__ bias, float* __restrict__ out) {
  __shared__ char smem[65536];   // 4 ring buffers x (A 8KB + B 8KB)

  const int m0 = blockIdx.x * 128, n0 = blockIdx.y * 128;
  const int t = threadIdx.x;
  const int lane = t & 63;
  const int w = t >> 6;          // 0..7
  const int quad = lane >> 4;
  const int l15 = lane & 15;
  const int wr = (w >> 2) * 64, wc = (w & 3) * 32;
  const int rswz = (quad ^ ((l15 >> 1) & 3)) * 8;

  const short* Abase = A + (size_t)m0 * DMODEL;
  const short* Bbase = Wz + (size_t)n0 * DMODEL;

  f32x4 acc[4][2] = {};

#pragma unroll
  for (int p = 0; p < 3; ++p) {
    stage_tile32_512(Abase + p * 32, (short(*)[32])(smem + p * 16384), t);
    stage_tile32_512(Bbase + p * 32, (short(*)[32])(smem + p * 16384 + 8192), t);
  }

  unsigned o0 = 0, o1 = 16384, o2 = 32768, o3 = 49152;
  for (int it = 0; it < 32; ++it) {
    if (it < 29) {
      const int kt = (it + 3) * 32;
      stage_tile32_512(Abase + kt, (short(*)[32])(smem + o3), t);
      stage_tile32_512(Bbase + kt, (short(*)[32])(smem + o3 + 8192), t);
    }
    if (it < 29)       asm volatile("s_waitcnt vmcnt(6)" ::: "memory");
    else if (it == 29) asm volatile("s_waitcnt vmcnt(4)" ::: "memory");
    else if (it == 30) asm volatile("s_waitcnt vmcnt(2)" ::: "memory");
    else               asm volatile("s_waitcnt vmcnt(0)" ::: "memory");
    __builtin_amdgcn_s_barrier();
    short (*As)[32] = (short(*)[32])(smem + o0);
    short (*Bs)[32] = (short(*)[32])(smem + o0 + 8192);
    bf16x8 bf[2], af[4];
#pragma unroll
    for (int nj = 0; nj < 2; ++nj)
      bf[nj] = *(const bf16x8*)&Bs[wc + nj * 16 + l15][rswz];
#pragma unroll
    for (int mi = 0; mi < 4; ++mi)
      af[mi] = *(const bf16x8*)&As[wr + mi * 16 + l15][rswz];
#pragma unroll
    for (int mi = 0; mi < 4; ++mi)
#pragma unroll
      for (int nj = 0; nj < 2; ++nj)
        acc[mi][nj] =
            __builtin_amdgcn_mfma_f32_16x16x32_bf16(af[mi], bf[nj], acc[mi][nj], 0, 0, 0);
    asm volatile("s_waitcnt lgkmcnt(0)" ::: "memory");
    __builtin_amdgcn_s_barrier();
    const unsigned tmp = o0; o0 = o1; o1 = o2; o2 = o3; o3 = tmp;
  }
#pragma unroll
  for (int nj = 0; nj < 2; ++nj) {
    const int n = n0 + wc + nj * 16 + l15;
    const float bval = bias[n];
#pragma unroll
    for (int ti = 0; ti < 4; ++ti)
#pragma unroll
      for (int r = 0; r < 4; ++r) {
        const int m = m0 + wr + ti * 16 + quad * 4 + r;
        out[(size_t)m * DMODEL + n] = acc[ti][nj][r] + bval;
      }
  }
}

// ---------------------------------------------------------------------------
extern "C" void kernel_launch(void* const* d_in, const int* in_sizes, int n_in,
                              void* d_out, int out_size, void* d_ws,
                              size_t ws_size, hipStream_t stream) {
  const float* q      = (const float*)d_in[0];
  const float* k      = (const float*)d_in[1];
  const float* v      = (const float*)d_in[2];
  const float* rope   = (const float*)d_in[3];
  const float* v_mask = (const float*)d_in[5];
  const float* Wq = (const float*)d_in[6];
  const float* bq = (const float*)d_in[7];
  const float* Wk = (const float*)d_in[8];
  const float* bk = (const float*)d_in[9];
  const float* Wv = (const float*)d_in[10];
  const float* bv = (const float*)d_in[11];
  const float* Wo = (const float*)d_in[12];
  const float* bo = (const float*)d_in[13];
  float* out = (float*)d_out;

  short* ws = (short*)d_ws;
  short* Qw = ws;                  // [bh][s][dk] bf16, 8 MB
  short* Kw = ws + 4194304;        // [bh][s][dk] bf16, 8 MB
  short* Vw = ws + 8388608;        // [bh][dk][s] bf16, 8 MB
  short* Ow = ws + 12582912;       // [b][s][dmodel] bf16, 8 MB
  short* Wt = ws + 16777216;       // 4x [n][k] bf16, 8 MB
  short* Xb = ws + 20971520;       // 3x [m][k] bf16, 24 MB  (total 64 MB)

  convert_xw<<<dim3(13312), 256, 0, stream>>>(q, k, v, Wq, Wk, Wv, Wo, Xb, Wt);
  gemm_qkv<<<dim3(32, 8, 3), 256, 0, stream>>>(Xb, Wt, bq, bk, bv, rope,
                                               Qw, Kw, Vw);
  attn_kernel<<<dim3(32, 32), 256, 0, stream>>>(Qw, Kw, Vw, v_mask, Ow);
  gemm_out<<<dim3(32, 8), 512, 0, stream>>>(Ow, Wt + 3145728, bo, out);
}